// Round 13
// baseline (150.011 us; speedup 1.0000x reference)
//
#include <hip/hip_runtime.h>
#include <hip/hip_bf16.h>

// Problem constants: B=2, S=2048, D_IN=1024, D_OUT=1024, H=16, Dh=64
#define B 2
#define S 2048
#define DIN 1024
#define DOUT 1024
#define NH 16
#define DH 64
#define M_TOT (B * S)   // 4096

typedef __attribute__((ext_vector_type(8))) short bf16x8;
typedef __attribute__((ext_vector_type(8))) unsigned short u16x8;
typedef __attribute__((ext_vector_type(4))) float f32x4;
typedef __attribute__((ext_vector_type(16))) float f32x16;

#define ASTRIDE 4194304   // elements per 4096x1024 split array
#define WSTRIDE 1048576   // elements per 1024x1024 split array

__device__ __forceinline__ ushort f2bf(float x) {
    union { float f; unsigned u; } c; c.f = x;
    unsigned r = (c.u + 0x7FFFu + ((c.u >> 16) & 1u)) >> 16;
    return (ushort)r;
}
__device__ __forceinline__ float bf2f(ushort h) {
    union { unsigned u; float f; } c; c.u = ((unsigned)h) << 16;
    return c.f;
}
__device__ __forceinline__ f32x4 mfma16(bf16x8 a, bf16x8 b, f32x4 c) {
    return __builtin_amdgcn_mfma_f32_16x16x32_bf16(a, b, c, 0, 0, 0);
}
__device__ __forceinline__ f32x16 mfma32(bf16x8 a, bf16x8 b, f32x16 c) {
    return __builtin_amdgcn_mfma_f32_32x32x16_bf16(a, b, c, 0, 0, 0);
}
__device__ __forceinline__ unsigned cvt_pk(float lo, float hi) {
    unsigned r;
    asm("v_cvt_pk_bf16_f32 %0, %1, %2" : "=v"(r) : "v"(lo), "v"(hi));
    return r;
}
__device__ __forceinline__ float exp2fast(float x) {
    float r;
    asm("v_exp_f32 %0, %1" : "=v"(r) : "v"(x));
    return r;
}

// ===========================================================================
// MAIN PATH (ws >= 68 MB)
// ===========================================================================

// ---- prepass: x (fp32 [4096][1024]) -> 2-way bf16 splits ----
__global__ __launch_bounds__(256) void split_x(const float* __restrict__ x,
                                               ushort* __restrict__ xs) {
    const size_t gid = (size_t)blockIdx.x * 256 + threadIdx.x;
    const float4 v = *reinterpret_cast<const float4*>(x + gid * 4);
    const float in[4] = {v.x, v.y, v.z, v.w};
    ushort h0[4], h1[4];
#pragma unroll
    for (int e = 0; e < 4; ++e) {
        h0[e] = f2bf(in[e]);
        h1[e] = f2bf(in[e] - bf2f(h0[e]));
    }
    const size_t o = gid * 4;
    *reinterpret_cast<ushort4*>(xs + o)           = ushort4{h0[0], h0[1], h0[2], h0[3]};
    *reinterpret_cast<ushort4*>(xs + ASTRIDE + o) = ushort4{h1[0], h1[1], h1[2], h1[3]};
}

// ---- prepass: all three W -> W^T 2-way bf16 splits, wt[wi][sp][n][k] ----
__global__ __launch_bounds__(256) void split_wT3(const float* __restrict__ W0,
                                                 const float* __restrict__ W1,
                                                 const float* __restrict__ W2,
                                                 ushort* __restrict__ wt) {
    __shared__ float Ws[64][68];
    const int tid = threadIdx.x;
    const int k0 = blockIdx.x << 6;
    const int n0 = blockIdx.y << 6;
    const int wi = blockIdx.z;
    const float* W = (wi == 0) ? W0 : (wi == 1) ? W1 : W2;
    ushort* wto = wt + (size_t)wi * 2 * WSTRIDE;

    const int r = tid >> 2;
    const int cb = (tid & 3) << 2;
#pragma unroll
    for (int it = 0; it < 4; ++it) {
        const int c = cb + (it << 4);
        *reinterpret_cast<float4*>(&Ws[r][c]) =
            *reinterpret_cast<const float4*>(&W[(size_t)(k0 + r) * 1024 + n0 + c]);
    }
    __syncthreads();
    const int rn = tid >> 2;
    const int kc = (tid & 3) << 4;
    u16x8 o0[2], o1[2];
#pragma unroll
    for (int half = 0; half < 2; ++half)
#pragma unroll
        for (int i = 0; i < 8; ++i) {
            const float x = Ws[kc + (half << 3) + i][rn];
            const ushort a = f2bf(x);
            o0[half][i] = a;
            o1[half][i] = f2bf(x - bf2f(a));
        }
    const size_t base = (size_t)(n0 + rn) * 1024 + k0 + kc;
    *reinterpret_cast<u16x8*>(wto + base)               = o0[0];
    *reinterpret_cast<u16x8*>(wto + base + 8)           = o0[1];
    *reinterpret_cast<u16x8*>(wto + WSTRIDE + base)     = o1[0];
    *reinterpret_cast<u16x8*>(wto + WSTRIDE + base + 8) = o1[1];
}

// ---------------------------------------------------------------------------
// Fused QKV projection v5 (UNCHANGED, verified r11): single 72 KB buffer,
// 2 barriers/step, 2 blocks/CU; Q/K 3-term, V 2-term; V^T via swapped-operand
// mfma16 with granule-permuted direct store.
// ---------------------------------------------------------------------------
__global__ __launch_bounds__(256, 2) void proj_fused5(const ushort* __restrict__ xsp,
                                                      const ushort* __restrict__ wtsp,
                                                      float* __restrict__ qf,
                                                      ushort* __restrict__ ksp,
                                                      ushort* __restrict__ vtsp) {
    __shared__ __align__(16) ushort SL[36864];   // 72 KB

    const int tid = threadIdx.x;
    const int lane = tid & 63;
    const int w = tid >> 6;
    const int swz = (blockIdx.x & 7) * 64 + (blockIdx.x >> 3);   // 512 blocks, bijective
    const int n0 = (swz & 15) << 6;
    const int m0 = (swz >> 4) << 7;   // 32 m-tiles of 128
    const int col = lane & 15;
    const int glane = lane >> 4;
    const int lrow = lane >> 3;
    const int sl8 = ((lane & 7) ^ lrow) << 3;

    f32x4 accq[2][4], acck[2][4], accv[2][4];   // [mi][nj]; accv is TRANSPOSED
#pragma unroll
    for (int mi = 0; mi < 2; ++mi)
#pragma unroll
        for (int nj = 0; nj < 4; ++nj) {
            accq[mi][nj] = f32x4{0.f, 0.f, 0.f, 0.f};
            acck[mi][nj] = f32x4{0.f, 0.f, 0.f, 0.f};
            accv[mi][nj] = f32x4{0.f, 0.f, 0.f, 0.f};
        }

    for (int k0 = 0; k0 < DIN; k0 += 64) {
        __syncthreads();   // previous step's LDS reads done
#pragma unroll
        for (int i = 0; i < 18; ++i) {
            const int u = (i << 2) | w;          // 0..71
            const ushort* g;
            if (u < 32) {
                const int sp = u >> 4, rb = u & 15;
                g = xsp + (size_t)sp * ASTRIDE + (size_t)(m0 + (rb << 3) + lrow) * 1024 + k0 + sl8;
            } else {
                const int v = u - 32;            // 0..39
                const int bi = v >> 3;           // 0..4 = Wq0,Wq1,Wk0,Wk1,Wv0
                const int rb = v & 7;
                g = wtsp + (size_t)bi * WSTRIDE + (size_t)(n0 + (rb << 3) + lrow) * 1024 + k0 + sl8;
            }
            __builtin_amdgcn_global_load_lds(g, &SL[u * 512], 16, 0, 0);
        }
        __syncthreads();   // staging drained + visible

#pragma unroll
        for (int st = 0; st < 2; ++st) {
            const int sw = (((st << 2) | glane) ^ (col & 7)) << 3;
            bf16x8 a[2][2];   // [sp][mi]
#pragma unroll
            for (int sp = 0; sp < 2; ++sp)
#pragma unroll
                for (int mi = 0; mi < 2; ++mi) {
                    const int arow = (w << 5) + (mi << 4) + col;
                    a[sp][mi] = *reinterpret_cast<const bf16x8*>(&SL[sp * 8192 + arow * 64 + sw]);
                }
#pragma unroll
            for (int nj = 0; nj < 4; ++nj) {
                const int brow = (nj << 4) + col;
                const int bb = 16384 + brow * 64 + sw;
                const bf16x8 bq0 = *reinterpret_cast<const bf16x8*>(&SL[bb]);
                const bf16x8 bq1 = *reinterpret_cast<const bf16x8*>(&SL[bb + 4096]);
                const bf16x8 bk0 = *reinterpret_cast<const bf16x8*>(&SL[bb + 8192]);
                const bf16x8 bk1 = *reinterpret_cast<const bf16x8*>(&SL[bb + 12288]);
                const bf16x8 bv0 = *reinterpret_cast<const bf16x8*>(&SL[bb + 16384]);
#pragma unroll
                for (int mi = 0; mi < 2; ++mi) {
                    accq[mi][nj] = mfma16(a[0][mi], bq0, accq[mi][nj]);
                    accq[mi][nj] = mfma16(a[1][mi], bq0, accq[mi][nj]);
                    accq[mi][nj] = mfma16(a[0][mi], bq1, accq[mi][nj]);
                    acck[mi][nj] = mfma16(a[0][mi], bk0, acck[mi][nj]);
                    acck[mi][nj] = mfma16(a[1][mi], bk0, acck[mi][nj]);
                    acck[mi][nj] = mfma16(a[0][mi], bk1, acck[mi][nj]);
                    accv[mi][nj] = mfma16(bv0, a[0][mi], accv[mi][nj]);
                    accv[mi][nj] = mfma16(bv0, a[1][mi], accv[mi][nj]);
                }
            }
        }
    }

    // ---- epilogue: Q fp32, K 2-split to [bh][s][d] ----
    const int b = m0 >> 11;
    const int h = n0 >> 6;
    const size_t bh_off = (size_t)(b * NH + h) * S * DH;
#pragma unroll
    for (int mi = 0; mi < 2; ++mi)
#pragma unroll
        for (int r = 0; r < 4; ++r) {
            const int srow = (m0 & (S - 1)) + (w << 5) + (mi << 4) + (glane << 2) + r;
#pragma unroll
            for (int nj = 0; nj < 4; ++nj) {
                const size_t o = bh_off + (size_t)srow * DH + (nj << 4) + col;
                qf[o] = accq[mi][nj][r];
                const float xk = acck[mi][nj][r];
                const ushort k0s = f2bf(xk);
                ksp[o] = k0s;
                ksp[ASTRIDE + o] = f2bf(xk - bf2f(k0s));
            }
        }

    // ---- V^T: direct register store to [bh][d][s'], granule-permuted ----
    const int cm = col >> 2;
    const int colp = (col & 3) | ((((cm & 1) << 1) | (cm >> 1)) << 2);
    const size_t vbh = (size_t)(b * NH + h) * DH * S;
#pragma unroll
    for (int mi = 0; mi < 2; ++mi) {
        const int s = (m0 & (S - 1)) + (w << 5) + (mi << 4) + colp;
#pragma unroll
        for (int nj = 0; nj < 4; ++nj)
#pragma unroll
            for (int r = 0; r < 4; ++r) {
                const int d = (nj << 4) + (glane << 2) + r;
                vtsp[vbh + (size_t)d * S + s] = f2bf(accv[mi][nj][r]);
            }
    }
}

// ---------------------------------------------------------------------------
// MFMA flash attention v9: WITHIN-BLOCK SPLIT-K for 2x wave parallelism.
// Block = 64 q-rows x 4 waves (256 thr). Waves {0,1} (half A) process the
// LOW half of the causal k-range for q-sub {lo,hi}; waves {2,3} (half B)
// the HIGH half. Each half has its own 24 KB staging buffer (K 2-split + V,
// 48 KB total -> 3 blocks/CU = 12 waves/CU vs the old 2/SIMD structural cap).
// Partials (O, m, l) merged in-LDS at block end (exp2(-inf)=0 handles empty
// halves). QK 3-term (k0q0+k0q1+k1q0); V 1-split; split-barrier prefetch;
// setprio around MFMA; balanced (15-j,16+j) CU pairing. Total loads/FLOPs
// unchanged vs v8.
// ---------------------------------------------------------------------------
__global__ __launch_bounds__(256, 3) void attn_mfma9(const float* __restrict__ Qf,
                                                     const ushort* __restrict__ ksp,
                                                     const ushort* __restrict__ vtsp,
                                                     float* __restrict__ out) {
    // per half: [ K0:4096 | K1:4096 | V:4096 ] ushorts = 24 KB; 48 KB total
    __shared__ __align__(16) ushort SB[2][12288];

    const int tid = threadIdx.x;
    const int lane = tid & 63;
    const int w = tid >> 6;                        // wave 0..3
    const int p = w & 1;                           // q-sub (0: rows 0-31, 1: 32-63)
    const int hf = w >> 1;                         // k-half (0: low, 1: high)

    // balanced bijective mapping (1024 blocks)
    const int xcd = blockIdx.x & 7;
    const int u_ = blockIdx.x >> 3;                // 0..127
    const int s_ = u_ & 31, p_ = u_ >> 5;          // CU slot, pass
    const int bh = (xcd << 2) | ((s_ >> 4) << 1) | (p_ >> 1);
    const int j_ = s_ & 15;
    const int qt = (p_ & 1) ? (16 + j_) : (15 - j_);   // 0..31

    const int q0 = qt << 6;                        // 64-row q tile
    const int qw0 = q0 + (p << 5);                 // wave's 32 q rows
    const int hi = lane >> 5;
    const int ql = lane & 31;
    const int qg = qw0 + ql;
    const int lrow = lane >> 3;
    const int sl8 = ((lane & 7) ^ lrow) << 3;

    // causal k-range split: half A = tiles [0, hA), half B = [hA, qt+1)
    const int hA = (qt + 2) >> 1;
    const int nT = hf ? (qt + 1 - hA) : hA;        // my half's tile count
    const int tbase = hf ? hA : 0;

    // ---- Q fragments: (1/8 * log2e) folded, 2 splits x 4 d-chunks ----
    bf16x8 qb[2][4];
    {
        const float* qp = Qf + ((size_t)bh * S + qg) * DH + (hi << 3);
#pragma unroll
        for (int dc = 0; dc < 4; ++dc) {
            const float4 f0 = *reinterpret_cast<const float4*>(qp + (dc << 4));
            const float4 f1 = *reinterpret_cast<const float4*>(qp + (dc << 4) + 4);
            const float xs[8] = {f0.x, f0.y, f0.z, f0.w, f1.x, f1.y, f1.z, f1.w};
#pragma unroll
            for (int e = 0; e < 8; ++e) {
                const float x = xs[e] * 0.18033688011112042f;   // 1/8 * log2(e)
                const ushort h0 = f2bf(x);
                qb[0][dc][e] = (short)h0;
                qb[1][dc][e] = (short)f2bf(x - bf2f(h0));
            }
        }
    }

    f32x16 O[2];
#pragma unroll
    for (int ds = 0; ds < 2; ++ds)
#pragma unroll
        for (int r = 0; r < 16; ++r) O[ds][r] = 0.f;
    float m_ = -INFINITY, l_ = 0.f;

    const size_t kbase = (size_t)bh * S * DH;
    const size_t vbase = (size_t)bh * DH * S;
    const int wl = p;   // local wave index within the half (0 or 1)

    // K: 16 units of 1 KB (2 splits x 8 row-blocks); V: 8 units. 2-wave coop.
#define ISSUE_K(K0)                                                                     \
    {                                                                                   \
        _Pragma("unroll")                                                               \
        for (int i = 0; i < 8; ++i) {                                                   \
            const int u = (i << 1) | wl;                                                \
            const int sp = u >> 3, rb = u & 7;                                          \
            const ushort* gp = ksp + (size_t)sp * ASTRIDE + kbase +                     \
                               (size_t)((K0) + (rb << 3) + lrow) * DH + sl8;            \
            __builtin_amdgcn_global_load_lds(gp, &SB[hf][sp * 4096 + (rb << 9)], 16, 0, 0); \
        }                                                                               \
    }
#define ISSUE_V(K0)                                                                     \
    {                                                                                   \
        _Pragma("unroll")                                                               \
        for (int i = 0; i < 4; ++i) {                                                   \
            const int u = (i << 1) | wl;                                                \
            const ushort* gp = vtsp + vbase +                                           \
                               (size_t)((u << 3) + lrow) * S + (K0) + sl8;              \
            __builtin_amdgcn_global_load_lds(gp, &SB[hf][8192 + (u << 9)], 16, 0, 0);   \
        }                                                                               \
    }

    if (nT > 0) { ISSUE_K(tbase << 6); ISSUE_V(tbase << 6); }
    __syncthreads();

    for (int kt = 0; kt < hA; ++kt) {
        const bool act = kt < nT;
        const int k0 = (tbase + kt) << 6;

        f32x16 Sf[2];
        if (act) {
#pragma unroll
            for (int ks = 0; ks < 2; ++ks)
#pragma unroll
                for (int r = 0; r < 16; ++r) Sf[ks][r] = 0.f;
            __builtin_amdgcn_s_setprio(1);
#pragma unroll
            for (int ks = 0; ks < 2; ++ks) {
#pragma unroll
                for (int dc = 0; dc < 4; ++dc) {
                    const int row = (ks << 5) + ql;
                    const int eo = row * 64 + ((((dc << 1) | hi) ^ (row & 7)) << 3);
                    const bf16x8 ka = *reinterpret_cast<const bf16x8*>(&SB[hf][eo]);
                    const bf16x8 kb = *reinterpret_cast<const bf16x8*>(&SB[hf][4096 + eo]);
                    Sf[ks] = mfma32(ka, qb[0][dc], Sf[ks]);
                    Sf[ks] = mfma32(ka, qb[1][dc], Sf[ks]);
                    Sf[ks] = mfma32(kb, qb[0][dc], Sf[ks]);
                }
            }
            __builtin_amdgcn_s_setprio(0);
        }

        __syncthreads();                     // all waves done reading K of this tile
        if (kt + 1 < nT) ISSUE_K(k0 + 64);   // prefetch under softmax+PV

        if (act) {
            // ---- causal mask (only near-diagonal tiles) ----
            if (k0 + 63 > qw0) {
#pragma unroll
                for (int ks = 0; ks < 2; ++ks)
#pragma unroll
                    for (int r = 0; r < 16; ++r) {
                        const int kg = k0 + (ks << 5) + (r & 3) + ((r >> 2) << 3) + (hi << 2);
                        if (kg > qg) Sf[ks][r] = -1e30f;
                    }
            }

            // ---- lane-local softmax, tree max, defer-max ----
            float mx[8];
#pragma unroll
            for (int i = 0; i < 8; ++i)
                mx[i] = fmaxf(fmaxf(Sf[0][i], Sf[0][i + 8]),
                              fmaxf(Sf[1][i], Sf[1][i + 8]));
            float rm = fmaxf(fmaxf(fmaxf(mx[0], mx[1]), fmaxf(mx[2], mx[3])),
                             fmaxf(fmaxf(mx[4], mx[5]), fmaxf(mx[6], mx[7])));
            rm = fmaxf(rm, __shfl_xor(rm, 32));
            if (__any(rm > m_ + 8.f)) {
                const float nm = fmaxf(m_, rm);
                const float sc = exp2fast(m_ - nm);
                m_ = nm;
                l_ *= sc;
#pragma unroll
                for (int ds = 0; ds < 2; ++ds)
#pragma unroll
                    for (int r = 0; r < 16; ++r) O[ds][r] *= sc;
            }

            // ---- P = 2^(S - m), tree sum, in-order B-frag packing ----
            float rsa[4] = {0.f, 0.f, 0.f, 0.f};
            bf16x8 pb[4];
#pragma unroll
            for (int ks = 0; ks < 2; ++ks) {
                float pv[16];
#pragma unroll
                for (int r = 0; r < 16; ++r) {
                    pv[r] = exp2fast(Sf[ks][r] - m_);
                    rsa[r & 3] += pv[r];
                }
#pragma unroll
                for (int c = 0; c < 2; ++c) {
                    union { unsigned u[4]; bf16x8 v; } pw;
                    pw.u[0] = cvt_pk(pv[(c << 3) + 0], pv[(c << 3) + 1]);
                    pw.u[1] = cvt_pk(pv[(c << 3) + 2], pv[(c << 3) + 3]);
                    pw.u[2] = cvt_pk(pv[(c << 3) + 4], pv[(c << 3) + 5]);
                    pw.u[3] = cvt_pk(pv[(c << 3) + 6], pv[(c << 3) + 7]);
                    pb[(ks << 1) + c] = pw.v;
                }
            }
            float rs = (rsa[0] + rsa[1]) + (rsa[2] + rsa[3]);
            rs += __shfl_xor(rs, 32);
            l_ += rs;

            // ---- O^T += V^T P^T ----
            __builtin_amdgcn_s_setprio(1);
#pragma unroll
            for (int ds = 0; ds < 2; ++ds)
#pragma unroll
                for (int kc = 0; kc < 4; ++kc) {
                    const int row = (ds << 5) + ql;
                    const int eo = row * 64 + ((((kc << 1) | hi) ^ (row & 7)) << 3);
                    const bf16x8 va = *reinterpret_cast<const bf16x8*>(&SB[hf][8192 + eo]);
                    O[ds] = mfma32(va, pb[kc], O[ds]);
                }
            __builtin_amdgcn_s_setprio(0);
        }

        __syncthreads();                     // V reads done; K(t+1) drained
        if (kt + 1 < nT) ISSUE_V(k0 + 64);   // prefetch under next QK
    }

    // ---- in-LDS combine of the two k-halves (pair: wave p <-> wave p+2) ----
    float* CF = reinterpret_cast<float*>(&SB[0][0]);   // 12288 floats avail
    if (hf == 1) {
        // half B writes partials: O at [((p*2+ds)*16+r)*64+lane], m/l at 4096+
#pragma unroll
        for (int ds = 0; ds < 2; ++ds)
#pragma unroll
            for (int r = 0; r < 16; ++r)
                CF[((p * 2 + ds) * 16 + r) * 64 + lane] = O[ds][r];
        if (lane < 32) {
            CF[4096 + p * 64 + lane * 2]     = m_;
            CF[4096 + p * 64 + lane * 2 + 1] = l_;
        }
    }
    __syncthreads();
    if (hf == 0) {
        const float mB = CF[4096 + p * 64 + ql * 2];
        const float lB = CF[4096 + p * 64 + ql * 2 + 1];
        const float m = fmaxf(m_, mB);
        const float sA = exp2fast(m_ - m);
        const float sB = exp2fast(mB - m);
        const float l = l_ * sA + lB * sB;
        const float inv = 1.f / l;
        const int b = bh >> 4, h = bh & (NH - 1);
        float* op = out + ((size_t)(b * S + qg)) * DOUT + h * DH;
#pragma unroll
        for (int ds = 0; ds < 2; ++ds)
#pragma unroll
            for (int rg = 0; rg < 4; ++rg) {
                float4 v;
#pragma unroll
                for (int e = 0; e < 4; ++e) {
                    const int r = (rg << 2) + e;
                    const float ob = CF[((p * 2 + ds) * 16 + r) * 64 + lane];
                    ((float*)&v)[e] = (O[ds][r] * sA + ob * sB) * inv;
                }
                *reinterpret_cast<float4*>(&op[(ds << 5) + (rg << 3) + (hi << 2)]) = v;
            }
    }
#undef ISSUE_K
#undef ISSUE_V
}

// ===========================================================================
// FALLBACK (fp32, ws >= 48 MB)
// ===========================================================================
__global__ __launch_bounds__(256) void proj_f32(const float* __restrict__ A,
                                                const float* __restrict__ W,
                                                float* __restrict__ outf) {
    __shared__ float As[16][68];
    __shared__ float Bs[16][68];
    const int tid = threadIdx.x;
    const int m0 = blockIdx.x * 64;
    const int n0 = blockIdx.y * 64;
    const int tm = tid >> 4, tn = tid & 15;
    const int la_r = tid >> 2, la_c = (tid & 3) << 2;
    const int lb_r = tid >> 4, lb_c = (tid & 15) << 2;

    float acc[4][4];
#pragma unroll
    for (int i = 0; i < 4; ++i)
#pragma unroll
        for (int j = 0; j < 4; ++j) acc[i][j] = 0.f;

    for (int k0 = 0; k0 < DIN; k0 += 16) {
        const float4 av = *reinterpret_cast<const float4*>(&A[(size_t)(m0 + la_r) * DIN + k0 + la_c]);
        const float4 bv = *reinterpret_cast<const float4*>(&W[(size_t)(k0 + lb_r) * DOUT + n0 + lb_c]);
        __syncthreads();
        As[la_c + 0][la_r] = av.x; As[la_c + 1][la_r] = av.y;
        As[la_c + 2][la_r] = av.z; As[la_c + 3][la_r] = av.w;
        *reinterpret_cast<float4*>(&Bs[lb_r][lb_c]) = bv;
        __syncthreads();
#pragma unroll
        for (int kk = 0; kk < 16; ++kk) {
            const float4 a = *reinterpret_cast<const float4*>(&As[kk][tm << 2]);
            const float4 b = *reinterpret_cast<const float4*>(&Bs[kk][tn << 2]);
            const float aa[4] = {a.x, a.y, a.z, a.w};
            const float bb[4] = {b.x, b.y, b.z, b.w};
#pragma unroll
            for (int i = 0; i < 4; ++i)
#pragma unroll
                for (int j = 0; j < 4; ++j) acc[i][j] += aa[i] * bb[j];
        }
    }
    const int b = m0 >> 11;
    const int s_base = (m0 & (S - 1)) + (tm << 2);
    const int h = n0 >> 6;
    const int dh = tn << 2;
    float* obase = outf + ((size_t)(b * NH + h) * S) * DH;
#pragma unroll
    for (int i = 0; i < 4; ++i) {
        float4 v;
        v.x = acc[i][0]; v.y = acc[i][1]; v.z = acc[i][2]; v.w = acc[i][3];
        *reinterpret_cast<float4*>(&obase[(size_t)(s_base + i) * DH + dh]) = v;
    }
}

__global__ __launch_bounds__(256) void attn_f32(const float* __restrict__ Q,
                                                const float* __restrict__ K,
                                                const float* __restrict__ V,
                                                float* __restrict__ out) {
    __shared__ float Qs[64][68];
    __shared__ float Ks[64][68];
    __shared__ float Vs[64][68];
    __shared__ float Ps[64][68];
    const int tid = threadIdx.x;
    const int bh = blockIdx.x & 31;
    const int qt = 31 - (blockIdx.x >> 5);
    const int q0 = qt << 6;
    const int tq = tid >> 4, tk = tid & 15;
    const int sr = tid >> 2, sc = (tid & 3) << 2;

    const float* qbase = Q + ((size_t)bh * S + q0) * DH;
    const float* kbase = K + (size_t)bh * S * DH;
    const float* vbase = V + (size_t)bh * S * DH;
#pragma unroll
    for (int it = 0; it < 4; ++it) {
        const int d0 = sc + (it << 4);
        const float4 v = *reinterpret_cast<const float4*>(&qbase[(size_t)sr * DH + d0]);
        Qs[d0 + 0][sr] = v.x; Qs[d0 + 1][sr] = v.y;
        Qs[d0 + 2][sr] = v.z; Qs[d0 + 3][sr] = v.w;
    }
    float C[4][4];
#pragma unroll
    for (int i = 0; i < 4; ++i)
#pragma unroll
        for (int j = 0; j < 4; ++j) C[i][j] = 0.f;
    float m[4] = {-1e30f, -1e30f, -1e30f, -1e30f};
    float l[4] = {0.f, 0.f, 0.f, 0.f};

    for (int kt = 0; kt <= qt; ++kt) {
        const int k0 = kt << 6;
        float4 kv[4], vv[4];
#pragma unroll
        for (int it = 0; it < 4; ++it) {
            const int d0 = sc + (it << 4);
            kv[it] = *reinterpret_cast<const float4*>(&kbase[(size_t)(k0 + sr) * DH + d0]);
            vv[it] = *reinterpret_cast<const float4*>(&vbase[(size_t)(k0 + sr) * DH + d0]);
        }
        __syncthreads();
#pragma unroll
        for (int it = 0; it < 4; ++it) {
            const int d0 = sc + (it << 4);
            Ks[d0 + 0][sr] = kv[it].x; Ks[d0 + 1][sr] = kv[it].y;
            Ks[d0 + 2][sr] = kv[it].z; Ks[d0 + 3][sr] = kv[it].w;
            *reinterpret_cast<float4*>(&Vs[sr][d0]) = vv[it];
        }
        __syncthreads();

        float s[4][4];
#pragma unroll
        for (int i = 0; i < 4; ++i)
#pragma unroll
            for (int j = 0; j < 4; ++j) s[i][j] = 0.f;
#pragma unroll 16
        for (int d = 0; d < 64; ++d) {
            const float4 qf4 = *reinterpret_cast<const float4*>(&Qs[d][tq << 2]);
            const float4 kf4 = *reinterpret_cast<const float4*>(&Ks[d][tk << 2]);
            const float qa[4] = {qf4.x, qf4.y, qf4.z, qf4.w};
            const float ka[4] = {kf4.x, kf4.y, kf4.z, kf4.w};
#pragma unroll
            for (int i = 0; i < 4; ++i)
#pragma unroll
                for (int j = 0; j < 4; ++j) s[i][j] += qa[i] * ka[j];
        }
        if (kt == qt) {
#pragma unroll
            for (int i = 0; i < 4; ++i) {
                const int qg = q0 + (tq << 2) + i;
#pragma unroll
                for (int j = 0; j < 4; ++j) {
                    const int kg = k0 + (tk << 2) + j;
                    s[i][j] = (kg <= qg) ? s[i][j] * 0.125f : -1e30f;
                }
            }
        } else {
#pragma unroll
            for (int i = 0; i < 4; ++i)
#pragma unroll
                for (int j = 0; j < 4; ++j) s[i][j] *= 0.125f;
        }
#pragma unroll
        for (int i = 0; i < 4; ++i) {
            float rm = fmaxf(fmaxf(s[i][0], s[i][1]), fmaxf(s[i][2], s[i][3]));
#pragma unroll
            for (int off = 1; off < 16; off <<= 1) rm = fmaxf(rm, __shfl_xor(rm, off));
            const float mn = fmaxf(m[i], rm);
            const float scale = __expf(m[i] - mn);
            float rs = 0.f;
#pragma unroll
            for (int j = 0; j < 4; ++j) {
                s[i][j] = __expf(s[i][j] - mn);
                rs += s[i][j];
            }
#pragma unroll
            for (int off = 1; off < 16; off <<= 1) rs += __shfl_xor(rs, off);
            l[i] = l[i] * scale + rs;
            m[i] = mn;
#pragma unroll
            for (int j = 0; j < 4; ++j) C[i][j] *= scale;
            *reinterpret_cast<float4*>(&Ps[(tq << 2) + i][tk << 2]) =
                make_float4(s[i][0], s[i][1], s[i][2], s[i][3]);
        }
        __syncthreads();
#pragma unroll 4
        for (int kc = 0; kc < 16; ++kc) {
            float4 pf[4], vf[4];
#pragma unroll
            for (int i = 0; i < 4; ++i)
                pf[i] = *reinterpret_cast<const float4*>(&Ps[(tq << 2) + i][kc << 2]);
#pragma unroll
            for (int j = 0; j < 4; ++j)
                vf[j] = *reinterpret_cast<const float4*>(&Vs[(kc << 2) + j][tk << 2]);
#pragma unroll
            for (int i = 0; i < 4; ++i) {
                const float pa[4] = {pf[i].x, pf[i].y, pf[i].z, pf[i].w};
#pragma unroll
                for (int j = 0; j < 4; ++j) {
                    C[i][j] += pa[0] * ((const float*)&vf[0])[j]
                             + pa[1] * ((const float*)&vf[1])[j]
                             + pa[2] * ((const float*)&vf[2])[j]
                             + pa[3] * ((const float*)&vf[3])[j];
                }
            }
        }
        __syncthreads();
    }
    const int b = bh >> 4, h = bh & (NH - 1);
#pragma unroll
    for (int i = 0; i < 4; ++i) {
        const int qg = q0 + (tq << 2) + i;
        const float inv = 1.f / l[i];
        float4 v;
        v.x = C[i][0] * inv; v.y = C[i][1] * inv;
        v.z = C[i][2] * inv; v.w = C[i][3] * inv;
        *reinterpret_cast<float4*>(&out[((size_t)(b * S + qg)) * DOUT + h * DH + (tk << 2)]) = v;
    }
}

// ===========================================================================
extern "C" void kernel_launch(void* const* d_in, const int* in_sizes, int n_in,
                              void* d_out, int out_size, void* d_ws, size_t ws_size,
                              hipStream_t stream) {
    const float* x  = (const float*)d_in[0];
    const float* Wq = (const float*)d_in[1];
    const float* Wk = (const float*)d_in[2];
    const float* Wv = (const float*)d_in[3];
    float* out = (float*)d_out;

    char* ws = (char*)d_ws;
    const size_t MB = 1024 * 1024;

    if (ws_size >= 68 * MB) {
        // layout: wT[0,12) | xsp 2-split[12,28) | Q[28,44) | K 2-split[44,60) |
        //         V^T bf16 1-split[60,68)
        ushort* wtsp = (ushort*)(ws);
        ushort* xsp  = (ushort*)(ws + 12 * MB);
        float*  qf   = (float*)(ws + 28 * MB);
        ushort* ksp  = (ushort*)(ws + 44 * MB);
        ushort* vtsp = (ushort*)(ws + 60 * MB);

        split_x<<<4096, 256, 0, stream>>>(x, xsp);
        split_wT3<<<dim3(16, 16, 3), 256, 0, stream>>>(Wq, Wk, Wv, wtsp);
        proj_fused5<<<512, 256, 0, stream>>>(xsp, wtsp, qf, ksp, vtsp);
        attn_mfma9<<<1024, 256, 0, stream>>>(qf, ksp, vtsp, out);
    } else {
        // fp32 fallback (48 MB)
        float* qws = (float*)d_ws;
        float* kws = qws + (size_t)M_TOT * DOUT;
        float* vws = kws + (size_t)M_TOT * DOUT;
        dim3 pgrid(M_TOT / 64, DOUT / 64);
        proj_f32<<<pgrid, 256, 0, stream>>>(x, Wq, qws);
        proj_f32<<<pgrid, 256, 0, stream>>>(x, Wk, kws);
        proj_f32<<<pgrid, 256, 0, stream>>>(x, Wv, vws);
        attn_f32<<<32 * 32, 256, 0, stream>>>(qws, kws, vws, out);
    }
}

// Round 14
// 129.889 us; speedup vs baseline: 1.1549x; 1.1549x over previous
//
#include <hip/hip_runtime.h>
#include <hip/hip_bf16.h>

// Problem constants: B=2, S=2048, D_IN=1024, D_OUT=1024, H=16, Dh=64
#define B 2
#define S 2048
#define DIN 1024
#define DOUT 1024
#define NH 16
#define DH 64
#define M_TOT (B * S)   // 4096

typedef __attribute__((ext_vector_type(8))) short bf16x8;
typedef __attribute__((ext_vector_type(8))) unsigned short u16x8;
typedef __attribute__((ext_vector_type(4))) float f32x4;
typedef __attribute__((ext_vector_type(16))) float f32x16;

#define ASTRIDE 4194304   // elements per 4096x1024 split array
#define WSTRIDE 1048576   // elements per 1024x1024 split array

__device__ __forceinline__ ushort f2bf(float x) {
    union { float f; unsigned u; } c; c.f = x;
    unsigned r = (c.u + 0x7FFFu + ((c.u >> 16) & 1u)) >> 16;
    return (ushort)r;
}
__device__ __forceinline__ float bf2f(ushort h) {
    union { unsigned u; float f; } c; c.u = ((unsigned)h) << 16;
    return c.f;
}
__device__ __forceinline__ f32x4 mfma16(bf16x8 a, bf16x8 b, f32x4 c) {
    return __builtin_amdgcn_mfma_f32_16x16x32_bf16(a, b, c, 0, 0, 0);
}
__device__ __forceinline__ f32x16 mfma32(bf16x8 a, bf16x8 b, f32x16 c) {
    return __builtin_amdgcn_mfma_f32_32x32x16_bf16(a, b, c, 0, 0, 0);
}
__device__ __forceinline__ unsigned cvt_pk(float lo, float hi) {
    unsigned r;
    asm("v_cvt_pk_bf16_f32 %0, %1, %2" : "=v"(r) : "v"(lo), "v"(hi));
    return r;
}
__device__ __forceinline__ float exp2fast(float x) {
    float r;
    asm("v_exp_f32 %0, %1" : "=v"(r) : "v"(x));
    return r;
}

// ===========================================================================
// MAIN PATH (ws >= 68 MB)
// ===========================================================================

// ---- prepass: x (fp32 [4096][1024]) -> 2-way bf16 splits ----
__global__ __launch_bounds__(256) void split_x(const float* __restrict__ x,
                                               ushort* __restrict__ xs) {
    const size_t gid = (size_t)blockIdx.x * 256 + threadIdx.x;
    const float4 v = *reinterpret_cast<const float4*>(x + gid * 4);
    const float in[4] = {v.x, v.y, v.z, v.w};
    ushort h0[4], h1[4];
#pragma unroll
    for (int e = 0; e < 4; ++e) {
        h0[e] = f2bf(in[e]);
        h1[e] = f2bf(in[e] - bf2f(h0[e]));
    }
    const size_t o = gid * 4;
    *reinterpret_cast<ushort4*>(xs + o)           = ushort4{h0[0], h0[1], h0[2], h0[3]};
    *reinterpret_cast<ushort4*>(xs + ASTRIDE + o) = ushort4{h1[0], h1[1], h1[2], h1[3]};
}

// ---- prepass: all three W -> W^T 2-way bf16 splits, wt[wi][sp][n][k] ----
__global__ __launch_bounds__(256) void split_wT3(const float* __restrict__ W0,
                                                 const float* __restrict__ W1,
                                                 const float* __restrict__ W2,
                                                 ushort* __restrict__ wt) {
    __shared__ float Ws[64][68];
    const int tid = threadIdx.x;
    const int k0 = blockIdx.x << 6;
    const int n0 = blockIdx.y << 6;
    const int wi = blockIdx.z;
    const float* W = (wi == 0) ? W0 : (wi == 1) ? W1 : W2;
    ushort* wto = wt + (size_t)wi * 2 * WSTRIDE;

    const int r = tid >> 2;
    const int cb = (tid & 3) << 2;
#pragma unroll
    for (int it = 0; it < 4; ++it) {
        const int c = cb + (it << 4);
        *reinterpret_cast<float4*>(&Ws[r][c]) =
            *reinterpret_cast<const float4*>(&W[(size_t)(k0 + r) * 1024 + n0 + c]);
    }
    __syncthreads();
    const int rn = tid >> 2;
    const int kc = (tid & 3) << 4;
    u16x8 o0[2], o1[2];
#pragma unroll
    for (int half = 0; half < 2; ++half)
#pragma unroll
        for (int i = 0; i < 8; ++i) {
            const float x = Ws[kc + (half << 3) + i][rn];
            const ushort a = f2bf(x);
            o0[half][i] = a;
            o1[half][i] = f2bf(x - bf2f(a));
        }
    const size_t base = (size_t)(n0 + rn) * 1024 + k0 + kc;
    *reinterpret_cast<u16x8*>(wto + base)               = o0[0];
    *reinterpret_cast<u16x8*>(wto + base + 8)           = o0[1];
    *reinterpret_cast<u16x8*>(wto + WSTRIDE + base)     = o1[0];
    *reinterpret_cast<u16x8*>(wto + WSTRIDE + base + 8) = o1[1];
}

// ---------------------------------------------------------------------------
// Fused QKV projection v5 (verified r11): single 72 KB buffer, 2 barriers/
// step, 2 blocks/CU; Q/K 3-term, V 2-term; V^T via swapped-operand mfma16
// with granule-permuted direct store.
// ---------------------------------------------------------------------------
__global__ __launch_bounds__(256, 2) void proj_fused5(const ushort* __restrict__ xsp,
                                                      const ushort* __restrict__ wtsp,
                                                      float* __restrict__ qf,
                                                      ushort* __restrict__ ksp,
                                                      ushort* __restrict__ vtsp) {
    __shared__ __align__(16) ushort SL[36864];   // 72 KB

    const int tid = threadIdx.x;
    const int lane = tid & 63;
    const int w = tid >> 6;
    const int swz = (blockIdx.x & 7) * 64 + (blockIdx.x >> 3);   // 512 blocks, bijective
    const int n0 = (swz & 15) << 6;
    const int m0 = (swz >> 4) << 7;   // 32 m-tiles of 128
    const int col = lane & 15;
    const int glane = lane >> 4;
    const int lrow = lane >> 3;
    const int sl8 = ((lane & 7) ^ lrow) << 3;

    f32x4 accq[2][4], acck[2][4], accv[2][4];   // [mi][nj]; accv is TRANSPOSED
#pragma unroll
    for (int mi = 0; mi < 2; ++mi)
#pragma unroll
        for (int nj = 0; nj < 4; ++nj) {
            accq[mi][nj] = f32x4{0.f, 0.f, 0.f, 0.f};
            acck[mi][nj] = f32x4{0.f, 0.f, 0.f, 0.f};
            accv[mi][nj] = f32x4{0.f, 0.f, 0.f, 0.f};
        }

    for (int k0 = 0; k0 < DIN; k0 += 64) {
        __syncthreads();   // previous step's LDS reads done
#pragma unroll
        for (int i = 0; i < 18; ++i) {
            const int u = (i << 2) | w;          // 0..71
            const ushort* g;
            if (u < 32) {
                const int sp = u >> 4, rb = u & 15;
                g = xsp + (size_t)sp * ASTRIDE + (size_t)(m0 + (rb << 3) + lrow) * 1024 + k0 + sl8;
            } else {
                const int v = u - 32;            // 0..39
                const int bi = v >> 3;           // 0..4 = Wq0,Wq1,Wk0,Wk1,Wv0
                const int rb = v & 7;
                g = wtsp + (size_t)bi * WSTRIDE + (size_t)(n0 + (rb << 3) + lrow) * 1024 + k0 + sl8;
            }
            __builtin_amdgcn_global_load_lds(g, &SL[u * 512], 16, 0, 0);
        }
        __syncthreads();   // staging drained + visible

#pragma unroll
        for (int st = 0; st < 2; ++st) {
            const int sw = (((st << 2) | glane) ^ (col & 7)) << 3;
            bf16x8 a[2][2];   // [sp][mi]
#pragma unroll
            for (int sp = 0; sp < 2; ++sp)
#pragma unroll
                for (int mi = 0; mi < 2; ++mi) {
                    const int arow = (w << 5) + (mi << 4) + col;
                    a[sp][mi] = *reinterpret_cast<const bf16x8*>(&SL[sp * 8192 + arow * 64 + sw]);
                }
#pragma unroll
            for (int nj = 0; nj < 4; ++nj) {
                const int brow = (nj << 4) + col;
                const int bb = 16384 + brow * 64 + sw;
                const bf16x8 bq0 = *reinterpret_cast<const bf16x8*>(&SL[bb]);
                const bf16x8 bq1 = *reinterpret_cast<const bf16x8*>(&SL[bb + 4096]);
                const bf16x8 bk0 = *reinterpret_cast<const bf16x8*>(&SL[bb + 8192]);
                const bf16x8 bk1 = *reinterpret_cast<const bf16x8*>(&SL[bb + 12288]);
                const bf16x8 bv0 = *reinterpret_cast<const bf16x8*>(&SL[bb + 16384]);
#pragma unroll
                for (int mi = 0; mi < 2; ++mi) {
                    accq[mi][nj] = mfma16(a[0][mi], bq0, accq[mi][nj]);
                    accq[mi][nj] = mfma16(a[1][mi], bq0, accq[mi][nj]);
                    accq[mi][nj] = mfma16(a[0][mi], bq1, accq[mi][nj]);
                    acck[mi][nj] = mfma16(a[0][mi], bk0, acck[mi][nj]);
                    acck[mi][nj] = mfma16(a[1][mi], bk0, acck[mi][nj]);
                    acck[mi][nj] = mfma16(a[0][mi], bk1, acck[mi][nj]);
                    accv[mi][nj] = mfma16(bv0, a[0][mi], accv[mi][nj]);
                    accv[mi][nj] = mfma16(bv0, a[1][mi], accv[mi][nj]);
                }
            }
        }
    }

    // ---- epilogue: Q fp32, K 2-split to [bh][s][d] ----
    const int b = m0 >> 11;
    const int h = n0 >> 6;
    const size_t bh_off = (size_t)(b * NH + h) * S * DH;
#pragma unroll
    for (int mi = 0; mi < 2; ++mi)
#pragma unroll
        for (int r = 0; r < 4; ++r) {
            const int srow = (m0 & (S - 1)) + (w << 5) + (mi << 4) + (glane << 2) + r;
#pragma unroll
            for (int nj = 0; nj < 4; ++nj) {
                const size_t o = bh_off + (size_t)srow * DH + (nj << 4) + col;
                qf[o] = accq[mi][nj][r];
                const float xk = acck[mi][nj][r];
                const ushort k0s = f2bf(xk);
                ksp[o] = k0s;
                ksp[ASTRIDE + o] = f2bf(xk - bf2f(k0s));
            }
        }

    // ---- V^T: direct register store to [bh][d][s'], granule-permuted ----
    const int cm = col >> 2;
    const int colp = (col & 3) | ((((cm & 1) << 1) | (cm >> 1)) << 2);
    const size_t vbh = (size_t)(b * NH + h) * DH * S;
#pragma unroll
    for (int mi = 0; mi < 2; ++mi) {
        const int s = (m0 & (S - 1)) + (w << 5) + (mi << 4) + colp;
#pragma unroll
        for (int nj = 0; nj < 4; ++nj)
#pragma unroll
            for (int r = 0; r < 4; ++r) {
                const int d = (nj << 4) + (glane << 2) + r;
                vtsp[vbh + (size_t)d * S + s] = f2bf(accv[mi][nj][r]);
            }
    }
}

// ---------------------------------------------------------------------------
// MFMA flash attention v8 (verified r12, best measured): QBLK=64, 2 waves/
// block, grid 1024 -> 4 blocks/CU; single 24 KB buffer, split-barrier
// prefetch; QK 4-term; V 1-split; setprio around MFMA clusters; balanced
// (15-j, 16+j) CU pairing.
// ---------------------------------------------------------------------------
__global__ __launch_bounds__(128, 2) void attn_mfma8(const float* __restrict__ Qf,
                                                     const ushort* __restrict__ ksp,
                                                     const ushort* __restrict__ vtsp,
                                                     float* __restrict__ out) {
    __shared__ __align__(16) ushort KL[2][4096];   // K splits, 16 KB
    __shared__ __align__(16) ushort VL[4096];      // V^T, 8 KB

    const int tid = threadIdx.x;
    const int lane = tid & 63;
    const int w = tid >> 6;                        // wave 0..1

    const int xcd = blockIdx.x & 7;
    const int u_ = blockIdx.x >> 3;                // 0..127
    const int s_ = u_ & 31, p_ = u_ >> 5;          // CU slot, pass
    const int bh = (xcd << 2) | ((s_ >> 4) << 1) | (p_ >> 1);
    const int j_ = s_ & 15;
    const int qt = (p_ & 1) ? (16 + j_) : (15 - j_);   // 0..31

    const int q0 = qt << 6;                        // 64-row q tile
    const int qw0 = q0 + (w << 5);                 // wave's 32 q rows
    const int hi = lane >> 5;
    const int ql = lane & 31;
    const int qg = qw0 + ql;
    const int lrow = lane >> 3;
    const int sl8 = ((lane & 7) ^ lrow) << 3;

    // ---- Q fragments: (1/8 * log2e) folded, 2 splits x 4 d-chunks ----
    bf16x8 qb[2][4];
    {
        const float* qp = Qf + ((size_t)bh * S + qg) * DH + (hi << 3);
#pragma unroll
        for (int dc = 0; dc < 4; ++dc) {
            const float4 f0 = *reinterpret_cast<const float4*>(qp + (dc << 4));
            const float4 f1 = *reinterpret_cast<const float4*>(qp + (dc << 4) + 4);
            const float xs[8] = {f0.x, f0.y, f0.z, f0.w, f1.x, f1.y, f1.z, f1.w};
#pragma unroll
            for (int e = 0; e < 8; ++e) {
                const float x = xs[e] * 0.18033688011112042f;   // 1/8 * log2(e)
                const ushort h0 = f2bf(x);
                qb[0][dc][e] = (short)h0;
                qb[1][dc][e] = (short)f2bf(x - bf2f(h0));
            }
        }
    }

    f32x16 O[2];
#pragma unroll
    for (int ds = 0; ds < 2; ++ds)
#pragma unroll
        for (int r = 0; r < 16; ++r) O[ds][r] = 0.f;
    float m_ = -INFINITY, l_ = 0.f;

    const size_t kbase = (size_t)bh * S * DH;
    const size_t vbase = (size_t)bh * DH * S;

#define ISSUE_K(K0)                                                                     \
    {                                                                                   \
        _Pragma("unroll")                                                               \
        for (int i = 0; i < 8; ++i) {                                                   \
            const int u = (i << 1) | w;                                                 \
            const int sp = u >> 3, rb = u & 7;                                          \
            const ushort* gp = ksp + (size_t)sp * ASTRIDE + kbase +                     \
                               (size_t)((K0) + (rb << 3) + lrow) * DH + sl8;            \
            __builtin_amdgcn_global_load_lds(gp, &KL[sp][rb << 9], 16, 0, 0);           \
        }                                                                               \
    }
#define ISSUE_V(K0)                                                                     \
    {                                                                                   \
        _Pragma("unroll")                                                               \
        for (int i = 0; i < 4; ++i) {                                                   \
            const int u = (i << 1) | w;                                                 \
            const ushort* gp = vtsp + vbase +                                           \
                               (size_t)((u << 3) + lrow) * S + (K0) + sl8;              \
            __builtin_amdgcn_global_load_lds(gp, &VL[u << 9], 16, 0, 0);                \
        }                                                                               \
    }

    ISSUE_K(0);
    ISSUE_V(0);
    __syncthreads();

    for (int kt = 0; kt <= qt; ++kt) {
        const int k0 = kt << 6;

        // ---- S^T = K Q^T (64k x 32q per wave, 4 split terms) ----
        f32x16 Sf[2];
#pragma unroll
        for (int ks = 0; ks < 2; ++ks)
#pragma unroll
            for (int r = 0; r < 16; ++r) Sf[ks][r] = 0.f;
        __builtin_amdgcn_s_setprio(1);
#pragma unroll
        for (int ks = 0; ks < 2; ++ks) {
#pragma unroll
            for (int dc = 0; dc < 4; ++dc) {
                const int row = (ks << 5) + ql;
                const int eo = row * 64 + ((((dc << 1) | hi) ^ (row & 7)) << 3);
                const bf16x8 ka = *reinterpret_cast<const bf16x8*>(&KL[0][eo]);
                const bf16x8 kb = *reinterpret_cast<const bf16x8*>(&KL[1][eo]);
                Sf[ks] = mfma32(ka, qb[0][dc], Sf[ks]);
                Sf[ks] = mfma32(ka, qb[1][dc], Sf[ks]);
                Sf[ks] = mfma32(kb, qb[0][dc], Sf[ks]);
                Sf[ks] = mfma32(kb, qb[1][dc], Sf[ks]);
            }
        }
        __builtin_amdgcn_s_setprio(0);

        __syncthreads();                 // all waves done reading K(t)
        if (kt < qt) ISSUE_K(k0 + 64);   // prefetch under softmax+PV

        // ---- causal mask (only near-diagonal tiles) ----
        if (k0 + 63 > qw0) {
#pragma unroll
            for (int ks = 0; ks < 2; ++ks)
#pragma unroll
                for (int r = 0; r < 16; ++r) {
                    const int kg = k0 + (ks << 5) + (r & 3) + ((r >> 2) << 3) + (hi << 2);
                    if (kg > qg) Sf[ks][r] = -1e30f;
                }
        }

        // ---- lane-local softmax, tree max, defer-max ----
        float mx[8];
#pragma unroll
        for (int i = 0; i < 8; ++i)
            mx[i] = fmaxf(fmaxf(Sf[0][i], Sf[0][i + 8]),
                          fmaxf(Sf[1][i], Sf[1][i + 8]));
        float rm = fmaxf(fmaxf(fmaxf(mx[0], mx[1]), fmaxf(mx[2], mx[3])),
                         fmaxf(fmaxf(mx[4], mx[5]), fmaxf(mx[6], mx[7])));
        rm = fmaxf(rm, __shfl_xor(rm, 32));
        if (__any(rm > m_ + 8.f)) {
            const float nm = fmaxf(m_, rm);
            const float sc = exp2fast(m_ - nm);
            m_ = nm;
            l_ *= sc;
#pragma unroll
            for (int ds = 0; ds < 2; ++ds)
#pragma unroll
                for (int r = 0; r < 16; ++r) O[ds][r] *= sc;
        }

        // ---- P = 2^(S - m), tree sum, in-order B-frag packing ----
        float rsa[4] = {0.f, 0.f, 0.f, 0.f};
        bf16x8 pb[4];
#pragma unroll
        for (int ks = 0; ks < 2; ++ks) {
            float p[16];
#pragma unroll
            for (int r = 0; r < 16; ++r) {
                p[r] = exp2fast(Sf[ks][r] - m_);
                rsa[r & 3] += p[r];
            }
#pragma unroll
            for (int c = 0; c < 2; ++c) {
                union { unsigned u[4]; bf16x8 v; } pw;
                pw.u[0] = cvt_pk(p[(c << 3) + 0], p[(c << 3) + 1]);
                pw.u[1] = cvt_pk(p[(c << 3) + 2], p[(c << 3) + 3]);
                pw.u[2] = cvt_pk(p[(c << 3) + 4], p[(c << 3) + 5]);
                pw.u[3] = cvt_pk(p[(c << 3) + 6], p[(c << 3) + 7]);
                pb[(ks << 1) + c] = pw.v;
            }
        }
        float rs = (rsa[0] + rsa[1]) + (rsa[2] + rsa[3]);
        rs += __shfl_xor(rs, 32);
        l_ += rs;

        // ---- O^T += V^T P^T ----
        __builtin_amdgcn_s_setprio(1);
#pragma unroll
        for (int ds = 0; ds < 2; ++ds)
#pragma unroll
            for (int kc = 0; kc < 4; ++kc) {
                const int row = (ds << 5) + ql;
                const int eo = row * 64 + ((((kc << 1) | hi) ^ (row & 7)) << 3);
                const bf16x8 va = *reinterpret_cast<const bf16x8*>(&VL[eo]);
                O[ds] = mfma32(va, pb[kc], O[ds]);
            }
        __builtin_amdgcn_s_setprio(0);

        __syncthreads();                 // all waves done reading V(t); K(t+1) drained
        if (kt < qt) ISSUE_V(k0 + 64);   // prefetch under next QK
    }

    // ---- epilogue: O^T[d, q] -> out[b, q, h*64 + d] ----
    const float inv = 1.f / l_;
    const int b = bh >> 4, h = bh & (NH - 1);
    float* op = out + ((size_t)(b * S + qg)) * DOUT + h * DH;
#pragma unroll
    for (int ds = 0; ds < 2; ++ds)
#pragma unroll
        for (int rg = 0; rg < 4; ++rg) {
            float4 v;
            v.x = O[ds][(rg << 2) + 0] * inv;
            v.y = O[ds][(rg << 2) + 1] * inv;
            v.z = O[ds][(rg << 2) + 2] * inv;
            v.w = O[ds][(rg << 2) + 3] * inv;
            *reinterpret_cast<float4*>(&op[(ds << 5) + (rg << 3) + (hi << 2)]) = v;
        }
#undef ISSUE_K
#undef ISSUE_V
}

// ===========================================================================
// FALLBACK (fp32, ws >= 48 MB)
// ===========================================================================
__global__ __launch_bounds__(256) void proj_f32(const float* __restrict__ A,
                                                const float* __restrict__ W,
                                                float* __restrict__ outf) {
    __shared__ float As[16][68];
    __shared__ float Bs[16][68];
    const int tid = threadIdx.x;
    const int m0 = blockIdx.x * 64;
    const int n0 = blockIdx.y * 64;
    const int tm = tid >> 4, tn = tid & 15;
    const int la_r = tid >> 2, la_c = (tid & 3) << 2;
    const int lb_r = tid >> 4, lb_c = (tid & 15) << 2;

    float acc[4][4];
#pragma unroll
    for (int i = 0; i < 4; ++i)
#pragma unroll
        for (int j = 0; j < 4; ++j) acc[i][j] = 0.f;

    for (int k0 = 0; k0 < DIN; k0 += 16) {
        const float4 av = *reinterpret_cast<const float4*>(&A[(size_t)(m0 + la_r) * DIN + k0 + la_c]);
        const float4 bv = *reinterpret_cast<const float4*>(&W[(size_t)(k0 + lb_r) * DOUT + n0 + lb_c]);
        __syncthreads();
        As[la_c + 0][la_r] = av.x; As[la_c + 1][la_r] = av.y;
        As[la_c + 2][la_r] = av.z; As[la_c + 3][la_r] = av.w;
        *reinterpret_cast<float4*>(&Bs[lb_r][lb_c]) = bv;
        __syncthreads();
#pragma unroll
        for (int kk = 0; kk < 16; ++kk) {
            const float4 a = *reinterpret_cast<const float4*>(&As[kk][tm << 2]);
            const float4 b = *reinterpret_cast<const float4*>(&Bs[kk][tn << 2]);
            const float aa[4] = {a.x, a.y, a.z, a.w};
            const float bb[4] = {b.x, b.y, b.z, b.w};
#pragma unroll
            for (int i = 0; i < 4; ++i)
#pragma unroll
                for (int j = 0; j < 4; ++j) acc[i][j] += aa[i] * bb[j];
        }
    }
    const int b = m0 >> 11;
    const int s_base = (m0 & (S - 1)) + (tm << 2);
    const int h = n0 >> 6;
    const int dh = tn << 2;
    float* obase = outf + ((size_t)(b * NH + h) * S) * DH;
#pragma unroll
    for (int i = 0; i < 4; ++i) {
        float4 v;
        v.x = acc[i][0]; v.y = acc[i][1]; v.z = acc[i][2]; v.w = acc[i][3];
        *reinterpret_cast<float4*>(&obase[(size_t)(s_base + i) * DH + dh]) = v;
    }
}

__global__ __launch_bounds__(256) void attn_f32(const float* __restrict__ Q,
                                                const float* __restrict__ K,
                                                const float* __restrict__ V,
                                                float* __restrict__ out) {
    __shared__ float Qs[64][68];
    __shared__ float Ks[64][68];
    __shared__ float Vs[64][68];
    __shared__ float Ps[64][68];
    const int tid = threadIdx.x;
    const int bh = blockIdx.x & 31;
    const int qt = 31 - (blockIdx.x >> 5);
    const int q0 = qt << 6;
    const int tq = tid >> 4, tk = tid & 15;
    const int sr = tid >> 2, sc = (tid & 3) << 2;

    const float* qbase = Q + ((size_t)bh * S + q0) * DH;
    const float* kbase = K + (size_t)bh * S * DH;
    const float* vbase = V + (size_t)bh * S * DH;
#pragma unroll
    for (int it = 0; it < 4; ++it) {
        const int d0 = sc + (it << 4);
        const float4 v = *reinterpret_cast<const float4*>(&qbase[(size_t)sr * DH + d0]);
        Qs[d0 + 0][sr] = v.x; Qs[d0 + 1][sr] = v.y;
        Qs[d0 + 2][sr] = v.z; Qs[d0 + 3][sr] = v.w;
    }
    float C[4][4];
#pragma unroll
    for (int i = 0; i < 4; ++i)
#pragma unroll
        for (int j = 0; j < 4; ++j) C[i][j] = 0.f;
    float m[4] = {-1e30f, -1e30f, -1e30f, -1e30f};
    float l[4] = {0.f, 0.f, 0.f, 0.f};

    for (int kt = 0; kt <= qt; ++kt) {
        const int k0 = kt << 6;
        float4 kv[4], vv[4];
#pragma unroll
        for (int it = 0; it < 4; ++it) {
            const int d0 = sc + (it << 4);
            kv[it] = *reinterpret_cast<const float4*>(&kbase[(size_t)(k0 + sr) * DH + d0]);
            vv[it] = *reinterpret_cast<const float4*>(&vbase[(size_t)(k0 + sr) * DH + d0]);
        }
        __syncthreads();
#pragma unroll
        for (int it = 0; it < 4; ++it) {
            const int d0 = sc + (it << 4);
            Ks[d0 + 0][sr] = kv[it].x; Ks[d0 + 1][sr] = kv[it].y;
            Ks[d0 + 2][sr] = kv[it].z; Ks[d0 + 3][sr] = kv[it].w;
            *reinterpret_cast<float4*>(&Vs[sr][d0]) = vv[it];
        }
        __syncthreads();

        float s[4][4];
#pragma unroll
        for (int i = 0; i < 4; ++i)
#pragma unroll
            for (int j = 0; j < 4; ++j) s[i][j] = 0.f;
#pragma unroll 16
        for (int d = 0; d < 64; ++d) {
            const float4 qf4 = *reinterpret_cast<const float4*>(&Qs[d][tq << 2]);
            const float4 kf4 = *reinterpret_cast<const float4*>(&Ks[d][tk << 2]);
            const float qa[4] = {qf4.x, qf4.y, qf4.z, qf4.w};
            const float ka[4] = {kf4.x, kf4.y, kf4.z, kf4.w};
#pragma unroll
            for (int i = 0; i < 4; ++i)
#pragma unroll
                for (int j = 0; j < 4; ++j) s[i][j] += qa[i] * ka[j];
        }
        if (kt == qt) {
#pragma unroll
            for (int i = 0; i < 4; ++i) {
                const int qg = q0 + (tq << 2) + i;
#pragma unroll
                for (int j = 0; j < 4; ++j) {
                    const int kg = k0 + (tk << 2) + j;
                    s[i][j] = (kg <= qg) ? s[i][j] * 0.125f : -1e30f;
                }
            }
        } else {
#pragma unroll
            for (int i = 0; i < 4; ++i)
#pragma unroll
                for (int j = 0; j < 4; ++j) s[i][j] *= 0.125f;
        }
#pragma unroll
        for (int i = 0; i < 4; ++i) {
            float rm = fmaxf(fmaxf(s[i][0], s[i][1]), fmaxf(s[i][2], s[i][3]));
#pragma unroll
            for (int off = 1; off < 16; off <<= 1) rm = fmaxf(rm, __shfl_xor(rm, off));
            const float mn = fmaxf(m[i], rm);
            const float scale = __expf(m[i] - mn);
            float rs = 0.f;
#pragma unroll
            for (int j = 0; j < 4; ++j) {
                s[i][j] = __expf(s[i][j] - mn);
                rs += s[i][j];
            }
#pragma unroll
            for (int off = 1; off < 16; off <<= 1) rs += __shfl_xor(rs, off);
            l[i] = l[i] * scale + rs;
            m[i] = mn;
#pragma unroll
            for (int j = 0; j < 4; ++j) C[i][j] *= scale;
            *reinterpret_cast<float4*>(&Ps[(tq << 2) + i][tk << 2]) =
                make_float4(s[i][0], s[i][1], s[i][2], s[i][3]);
        }
        __syncthreads();
#pragma unroll 4
        for (int kc = 0; kc < 16; ++kc) {
            float4 pf[4], vf[4];
#pragma unroll
            for (int i = 0; i < 4; ++i)
                pf[i] = *reinterpret_cast<const float4*>(&Ps[(tq << 2) + i][kc << 2]);
#pragma unroll
            for (int j = 0; j < 4; ++j)
                vf[j] = *reinterpret_cast<const float4*>(&Vs[(kc << 2) + j][tk << 2]);
#pragma unroll
            for (int i = 0; i < 4; ++i) {
                const float pa[4] = {pf[i].x, pf[i].y, pf[i].z, pf[i].w};
#pragma unroll
                for (int j = 0; j < 4; ++j) {
                    C[i][j] += pa[0] * ((const float*)&vf[0])[j]
                             + pa[1] * ((const float*)&vf[1])[j]
                             + pa[2] * ((const float*)&vf[2])[j]
                             + pa[3] * ((const float*)&vf[3])[j];
                }
            }
        }
        __syncthreads();
    }
    const int b = bh >> 4, h = bh & (NH - 1);
#pragma unroll
    for (int i = 0; i < 4; ++i) {
        const int qg = q0 + (tq << 2) + i;
        const float inv = 1.f / l[i];
        float4 v;
        v.x = C[i][0] * inv; v.y = C[i][1] * inv;
        v.z = C[i][2] * inv; v.w = C[i][3] * inv;
        *reinterpret_cast<float4*>(&out[((size_t)(b * S + qg)) * DOUT + h * DH + (tk << 2)]) = v;
    }
}

// ===========================================================================
extern "C" void kernel_launch(void* const* d_in, const int* in_sizes, int n_in,
                              void* d_out, int out_size, void* d_ws, size_t ws_size,
                              hipStream_t stream) {
    const float* x  = (const float*)d_in[0];
    const float* Wq = (const float*)d_in[1];
    const float* Wk = (const float*)d_in[2];
    const float* Wv = (const float*)d_in[3];
    float* out = (float*)d_out;

    char* ws = (char*)d_ws;
    const size_t MB = 1024 * 1024;

    if (ws_size >= 68 * MB) {
        // layout: wT[0,12) | xsp 2-split[12,28) | Q[28,44) | K 2-split[44,60) |
        //         V^T bf16 1-split[60,68)
        ushort* wtsp = (ushort*)(ws);
        ushort* xsp  = (ushort*)(ws + 12 * MB);
        float*  qf   = (float*)(ws + 28 * MB);
        ushort* ksp  = (ushort*)(ws + 44 * MB);
        ushort* vtsp = (ushort*)(ws + 60 * MB);

        split_x<<<4096, 256, 0, stream>>>(x, xsp);
        split_wT3<<<dim3(16, 16, 3), 256, 0, stream>>>(Wq, Wk, Wv, wtsp);
        proj_fused5<<<512, 256, 0, stream>>>(xsp, wtsp, qf, ksp, vtsp);
        attn_mfma8<<<1024, 128, 0, stream>>>(qf, ksp, vtsp, out);
    } else {
        // fp32 fallback (48 MB)
        float* qws = (float*)d_ws;
        float* kws = qws + (size_t)M_TOT * DOUT;
        float* vws = kws + (size_t)M_TOT * DOUT;
        dim3 pgrid(M_TOT / 64, DOUT / 64);
        proj_f32<<<pgrid, 256, 0, stream>>>(x, Wq, qws);
        proj_f32<<<pgrid, 256, 0, stream>>>(x, Wk, kws);
        proj_f32<<<pgrid, 256, 0, stream>>>(x, Wv, vws);
        attn_f32<<<32 * 32, 256, 0, stream>>>(qws, kws, vws, out);
    }
}